// Round 3
// baseline (331.862 us; speedup 1.0000x reference)
//
#include <hip/hip_runtime.h>
#include <math.h>

// RBF: out[m][n] = v * exp(-0.5*max(xn[m]+yn[n]-2*cross, 0)), N=M=8192, D=64.
// R2 design: NO LDS tiles. MFMA fragments loaded directly global->register
// (D=64: a fragment is 8 consecutive floats of one row; tiles are L2-resident),
// split-bf16 hi/lo in-register (3 MFMAs, fp32 accum; d2 err ~1e-4 vs 0.04 budget).
// Operands swapped (X2 = A-op, X = B-op) so the C/D layout yields 4 consecutive
// n per reg-quad -> dwordx4 stores. Target: HBM write floor (256 MB, ~41 us).
#define MM 8192
#define DD 64

typedef __bf16 bf16x8 __attribute__((ext_vector_type(8)));
typedef float f32x4 __attribute__((ext_vector_type(4)));

__device__ __forceinline__ float softplus_f(float x) {
    // logaddexp(x, 0) = max(x,0) + log1p(exp(-|x|)), fp32-stable
    return fmaxf(x, 0.0f) + log1pf(exp2f(-fabsf(x) * 1.4426950408889634f));
}

__device__ __forceinline__ void split8(float4 p0, float4 p1, bf16x8& h, bf16x8& l) {
    h[0] = (__bf16)p0.x; l[0] = (__bf16)(p0.x - (float)h[0]);
    h[1] = (__bf16)p0.y; l[1] = (__bf16)(p0.y - (float)h[1]);
    h[2] = (__bf16)p0.z; l[2] = (__bf16)(p0.z - (float)h[2]);
    h[3] = (__bf16)p0.w; l[3] = (__bf16)(p0.w - (float)h[3]);
    h[4] = (__bf16)p1.x; l[4] = (__bf16)(p1.x - (float)h[4]);
    h[5] = (__bf16)p1.y; l[5] = (__bf16)(p1.y - (float)h[5]);
    h[6] = (__bf16)p1.z; l[6] = (__bf16)(p1.z - (float)h[6]);
    h[7] = (__bf16)p1.w; l[7] = (__bf16)(p1.w - (float)h[7]);
}

__global__ __launch_bounds__(256, 2)
void rbf_mfma2(const float* __restrict__ X, const float* __restrict__ X2,
               const float* __restrict__ raw_l, const float* __restrict__ raw_v,
               float* __restrict__ out) {
    __shared__ float ls2[DD];   // 1/softplus(raw_l)^2
    __shared__ float xn[128];
    __shared__ float yn[128];

    const int t  = threadIdx.x;
    const int bn = blockIdx.x;
    const int bm = blockIdx.y;

    if (t < DD) { float il = 1.0f / softplus_f(raw_l[t]); ls2[t] = il * il; }
    __syncthreads();

    // ---- exact fp32 row norms: xn[m] = sum x^2/l^2, yn[n] = sum y^2/l^2 ----
    {
        const int r = t & 127;
        const float* p = (t < 128) ? (X + (size_t)(bm * 128 + r) * DD)
                                   : (X2 + (size_t)(bn * 128 + r) * DD);
        float s = 0.0f;
#pragma unroll
        for (int j = 0; j < 16; ++j) {
            float4 a = ((const float4*)p)[j];
            s = fmaf(a.x * a.x, ls2[4 * j + 0], s);
            s = fmaf(a.y * a.y, ls2[4 * j + 1], s);
            s = fmaf(a.z * a.z, ls2[4 * j + 2], s);
            s = fmaf(a.w * a.w, ls2[4 * j + 3], s);
        }
        if (t < 128) xn[r] = s; else yn[r] = s;
    }
    __syncthreads();

    // ---- per-wave 64(m) x 64(n) quadrant; frags straight from global ----
    const int lane = t & 63;
    const int q    = lane >> 4;   // 0..3
    const int r16  = lane & 15;   // 0..15
    const int w    = t >> 6;      // 0..3
    const int mw   = (w & 1) * 64;
    const int nw   = (w >> 1) * 64;

    const float* Xb  = X  + (size_t)(bm * 128 + mw) * DD;  // m rows (B-operand)
    const float* X2b = X2 + (size_t)(bn * 128 + nw) * DD;  // n rows (A-operand)

    f32x4 acc[4][4];  // [ni][mi]
#pragma unroll
    for (int ni = 0; ni < 4; ++ni)
#pragma unroll
        for (int mi = 0; mi < 4; ++mi)
#pragma unroll
            for (int r = 0; r < 4; ++r) acc[ni][mi][r] = 0.0f;

#pragma unroll
    for (int kc = 0; kc < 2; ++kc) {
        const int k0 = kc * 32 + q * 8;
        // X-side scale vector (wave-uniform per quad; LDS broadcast)
        float4 s0 = *(const float4*)&ls2[k0];
        float4 s1 = *(const float4*)&ls2[k0 + 4];

        bf16x8 ah[4], al[4], xh[4], xl[4];
#pragma unroll
        for (int i = 0; i < 4; ++i) {
            const float* pa = X2b + (i * 16 + r16) * DD + k0;
            float4 p0 = *(const float4*)pa;
            float4 p1 = *(const float4*)(pa + 4);
            split8(p0, p1, ah[i], al[i]);

            const float* pb = Xb + (i * 16 + r16) * DD + k0;
            float4 q0 = *(const float4*)pb;
            float4 q1 = *(const float4*)(pb + 4);
            q0.x *= s0.x; q0.y *= s0.y; q0.z *= s0.z; q0.w *= s0.w;
            q1.x *= s1.x; q1.y *= s1.y; q1.z *= s1.z; q1.w *= s1.w;
            split8(q0, q1, xh[i], xl[i]);
        }
#pragma unroll
        for (int ni = 0; ni < 4; ++ni) {
#pragma unroll
            for (int mi = 0; mi < 4; ++mi) {
                acc[ni][mi] = __builtin_amdgcn_mfma_f32_16x16x32_bf16(ah[ni], xh[mi], acc[ni][mi], 0, 0, 0);
                acc[ni][mi] = __builtin_amdgcn_mfma_f32_16x16x32_bf16(ah[ni], xl[mi], acc[ni][mi], 0, 0, 0);
                acc[ni][mi] = __builtin_amdgcn_mfma_f32_16x16x32_bf16(al[ni], xh[mi], acc[ni][mi], 0, 0, 0);
            }
        }
    }

    // ---- epilogue: lane holds out[m = mw+mi*16+r16][n = nw+ni*16+q*4 + 0..3] ----
    const float v  = softplus_f(raw_v[0]);
    const float ce = -0.5f * 1.4426950408889634f;  // exp(-0.5 d2) = exp2(ce*d2)

#pragma unroll
    for (int ni = 0; ni < 4; ++ni) {
        float4 yv = *(const float4*)&yn[nw + ni * 16 + q * 4];
        const int ncol = bn * 128 + nw + ni * 16 + q * 4;
#pragma unroll
        for (int mi = 0; mi < 4; ++mi) {
            const int ml = mw + mi * 16 + r16;
            const float xr = xn[ml];
            f32x4 a = acc[ni][mi];
            float4 o;
            float d;
            // d2raw<0 handled: ce<0 so min(ce*d2raw,0) == ce*max(d2raw,0)
            d = fminf(ce * (xr + yv.x - 2.0f * a[0]), 0.0f); o.x = v * exp2f(d);
            d = fminf(ce * (xr + yv.y - 2.0f * a[1]), 0.0f); o.y = v * exp2f(d);
            d = fminf(ce * (xr + yv.z - 2.0f * a[2]), 0.0f); o.z = v * exp2f(d);
            d = fminf(ce * (xr + yv.w - 2.0f * a[3]), 0.0f); o.w = v * exp2f(d);
            *(float4*)(out + (size_t)(bm * 128 + ml) * MM + ncol) = o;
        }
    }
}

extern "C" void kernel_launch(void* const* d_in, const int* in_sizes, int n_in,
                              void* d_out, int out_size, void* d_ws, size_t ws_size,
                              hipStream_t stream) {
    const float* X     = (const float*)d_in[0];
    const float* X2    = (const float*)d_in[1];
    const float* raw_l = (const float*)d_in[2];
    const float* raw_v = (const float*)d_in[3];
    float* out = (float*)d_out;

    dim3 grid(MM / 128, MM / 128);  // (64, 64)
    dim3 block(256);
    rbf_mfma2<<<grid, block, 0, stream>>>(X, X2, raw_l, raw_v, out);
}